// Round 1
// baseline (4420.634 us; speedup 1.0000x reference)
//
#include <hip/hip_runtime.h>
#include <math.h>

// Problem constants
#define BATCH   32768
#define DIMX    64
#define FEATD   128
#define IN1     192      // FEATDIM + DIM
#define WIDTH   1536
#define ONC     896      // DIM * (3K-1)

// Tiling
#define BM      16       // batch rows per block
#define NT      512      // threads per block (8 waves)
#define NJ      3        // columns per thread in WIDTH-wide gemms (3*512 = 1536)

__device__ __forceinline__ float wave_sum64(float v) {
  #pragma unroll
  for (int off = 32; off > 0; off >>= 1) v += __shfl_xor(v, off, 64);
  return v;
}

__device__ __forceinline__ float softplusf(float t) {
  // exact: max(t,0) + log1p(exp(-|t|))
  return fmaxf(t, 0.0f) + log1pf(expf(-fabsf(t)));
}

// ---------------------------------------------------------------------------
// Transpose [R][C] row-major -> [C][R] row-major (k-major weights for
// coalesced lane-contiguous reads in the GEMM inner loops).
// ---------------------------------------------------------------------------
__global__ __launch_bounds__(256) void transpose_k(const float* __restrict__ in,
                                                   float* __restrict__ out,
                                                   int R, int C) {
  __shared__ float tile[32][33];
  const int cx = blockIdx.x * 32, ry = blockIdx.y * 32;
  const int tx = threadIdx.x & 31, ty = threadIdx.x >> 5;   // 32 x 8
  #pragma unroll
  for (int i = 0; i < 4; ++i) {
    int r = ry + ty + i * 8, c = cx + tx;
    if (r < R && c < C) tile[ty + i * 8][tx] = in[(size_t)r * C + c];
  }
  __syncthreads();
  #pragma unroll
  for (int i = 0; i < 4; ++i) {
    int c = cx + ty + i * 8, r = ry + tx;
    if (r < R && c < C) out[(size_t)c * R + r] = tile[tx][ty + i * 8];
  }
}

// ---------------------------------------------------------------------------
// bias + leaky_relu + LayerNorm over the 1536 columns, result into hs[r][j].
// ---------------------------------------------------------------------------
__device__ __forceinline__ void act_ln(float acc[BM][NJ],
    const float* __restrict__ bias, const float* __restrict__ gam,
    const float* __restrict__ bet, float* hs, float* red, float* mstd,
    int t, int lane, int wid)
{
  float gg[NJ], ee[NJ];
  #pragma unroll
  for (int j = 0; j < NJ; ++j) {
    const int col = t + NT * j;
    const float bb = bias[col];
    gg[j] = gam[col]; ee[j] = bet[col];
    #pragma unroll
    for (int r = 0; r < BM; ++r) {
      float v = acc[r][j] + bb;
      acc[r][j] = v > 0.f ? v : 0.2f * v;      // leaky_relu(.,0.2) BEFORE LN
    }
  }
  #pragma unroll
  for (int r = 0; r < BM; ++r) {
    float s = acc[r][0] + acc[r][1] + acc[r][2];
    float q = acc[r][0] * acc[r][0] + acc[r][1] * acc[r][1] + acc[r][2] * acc[r][2];
    s = wave_sum64(s);
    q = wave_sum64(q);
    if (lane == 0) { red[wid * 32 + r] = s; red[wid * 32 + 16 + r] = q; }
  }
  __syncthreads();                 // also guarantees every thread finished its GEMM reads
  if (t < BM) {
    float s = 0.f, q = 0.f;
    #pragma unroll
    for (int w = 0; w < NT / 64; ++w) { s += red[w * 32 + t]; q += red[w * 32 + 16 + t]; }
    const float m = s * (1.0f / (float)WIDTH);
    const float v = q * (1.0f / (float)WIDTH) - m * m;
    mstd[t]      = m;
    mstd[16 + t] = rsqrtf(fmaxf(v, 0.f) + 1e-5f);
  }
  __syncthreads();
  #pragma unroll
  for (int r = 0; r < BM; ++r) {
    const float m = mstd[r], rs = mstd[16 + r];
    #pragma unroll
    for (int j = 0; j < NJ; ++j)
      hs[r * WIDTH + t + NT * j] = (acc[r][j] - m) * rs * gg[j] + ee[j];
  }
  __syncthreads();
}

// ---------------------------------------------------------------------------
// Fully fused: concat -> gemm1 -> act/LN -> gemm2 -> act/LN -> gemm3 -> spline
// ---------------------------------------------------------------------------
__global__ __launch_bounds__(NT) void nsf_fused(
    const float* __restrict__ x, const float* __restrict__ feat,
    const float* __restrict__ w1t, const float* __restrict__ b1,
    const float* __restrict__ g1, const float* __restrict__ be1,
    const float* __restrict__ w2t, const float* __restrict__ b2,
    const float* __restrict__ g2, const float* __restrict__ be2,
    const float* __restrict__ w3t, const float* __restrict__ b3,
    float* __restrict__ zout, float* __restrict__ ladout)
{
  __shared__ float hs[BM * WIDTH];          // 96 KB: input stage / h / o (aliased)
  __shared__ float red[(NT / 64) * 32];
  __shared__ float mstd[32];

  const int t = threadIdx.x;
  const int lane = t & 63, wid = t >> 6;
  const int b0 = blockIdx.x * BM;

  // ---- stage concat([feat, x]) tile: [BM][IN1] packed at front of hs ----
  for (int i = t; i < BM * IN1; i += NT) {
    const int r = i / IN1, c = i - r * IN1;
    hs[i] = (c < FEATD) ? feat[(size_t)(b0 + r) * FEATD + c]
                        : x[(size_t)(b0 + r) * DIMX + (c - FEATD)];
  }
  __syncthreads();

  float acc[BM][NJ];
  #pragma unroll
  for (int r = 0; r < BM; ++r)
    #pragma unroll
    for (int j = 0; j < NJ; ++j) acc[r][j] = 0.f;

  // ---- GEMM1: K = 192 ----
  #pragma unroll 2
  for (int kk = 0; kk < IN1; kk += 4) {
    float wv[4][NJ];
    #pragma unroll
    for (int u = 0; u < 4; ++u) {
      const float* wr = w1t + (size_t)(kk + u) * WIDTH + t;
      #pragma unroll
      for (int j = 0; j < NJ; ++j) wv[u][j] = wr[NT * j];
    }
    #pragma unroll
    for (int r = 0; r < BM; ++r) {
      const float4 av = *(const float4*)&hs[r * IN1 + kk];   // LDS broadcast
      #pragma unroll
      for (int j = 0; j < NJ; ++j) {
        acc[r][j] = fmaf(av.x, wv[0][j], acc[r][j]);
        acc[r][j] = fmaf(av.y, wv[1][j], acc[r][j]);
        acc[r][j] = fmaf(av.z, wv[2][j], acc[r][j]);
        acc[r][j] = fmaf(av.w, wv[3][j], acc[r][j]);
      }
    }
  }
  act_ln(acc, b1, g1, be1, hs, red, mstd, t, lane, wid);

  #pragma unroll
  for (int r = 0; r < BM; ++r)
    #pragma unroll
    for (int j = 0; j < NJ; ++j) acc[r][j] = 0.f;

  // ---- GEMM2: K = 1536 ----
  #pragma unroll 2
  for (int kk = 0; kk < WIDTH; kk += 4) {
    float wv[4][NJ];
    #pragma unroll
    for (int u = 0; u < 4; ++u) {
      const float* wr = w2t + (size_t)(kk + u) * WIDTH + t;
      #pragma unroll
      for (int j = 0; j < NJ; ++j) wv[u][j] = wr[NT * j];
    }
    #pragma unroll
    for (int r = 0; r < BM; ++r) {
      const float4 av = *(const float4*)&hs[r * WIDTH + kk];
      #pragma unroll
      for (int j = 0; j < NJ; ++j) {
        acc[r][j] = fmaf(av.x, wv[0][j], acc[r][j]);
        acc[r][j] = fmaf(av.y, wv[1][j], acc[r][j]);
        acc[r][j] = fmaf(av.z, wv[2][j], acc[r][j]);
        acc[r][j] = fmaf(av.w, wv[3][j], acc[r][j]);
      }
    }
  }
  act_ln(acc, b2, g2, be2, hs, red, mstd, t, lane, wid);

  // ---- GEMM3: N = 896 (cols t and, for t<384, t+512) ----
  const bool has2 = (t < ONC - NT);
  #pragma unroll
  for (int r = 0; r < BM; ++r) { acc[r][0] = 0.f; acc[r][1] = 0.f; }
  #pragma unroll 2
  for (int kk = 0; kk < WIDTH; kk += 4) {
    float wv[4][2];
    #pragma unroll
    for (int u = 0; u < 4; ++u) {
      const float* wr = w3t + (size_t)(kk + u) * ONC + t;
      wv[u][0] = wr[0];
      wv[u][1] = has2 ? wr[NT] : 0.f;
    }
    #pragma unroll
    for (int r = 0; r < BM; ++r) {
      const float4 av = *(const float4*)&hs[r * WIDTH + kk];
      acc[r][0] = fmaf(av.x, wv[0][0], acc[r][0]);
      acc[r][0] = fmaf(av.y, wv[1][0], acc[r][0]);
      acc[r][0] = fmaf(av.z, wv[2][0], acc[r][0]);
      acc[r][0] = fmaf(av.w, wv[3][0], acc[r][0]);
      acc[r][1] = fmaf(av.x, wv[0][1], acc[r][1]);
      acc[r][1] = fmaf(av.y, wv[1][1], acc[r][1]);
      acc[r][1] = fmaf(av.z, wv[2][1], acc[r][1]);
      acc[r][1] = fmaf(av.w, wv[3][1], acc[r][1]);
    }
  }
  __syncthreads();                 // all reads of h2 done before o overwrites hs
  {
    const float bb0 = b3[t];
    const float bb1 = has2 ? b3[t + NT] : 0.f;
    #pragma unroll
    for (int r = 0; r < BM; ++r) {
      hs[r * ONC + t] = acc[r][0] + bb0;
      if (has2) hs[r * ONC + t + NT] = acc[r][1] + bb1;
    }
  }
  __syncthreads();

  // ---- spline: wave `wid` handles rows 2*wid, 2*wid+1; lane = dim ----
  #pragma unroll
  for (int i = 0; i < BM / (NT / 64); ++i) {
    const int r = wid * 2 + i;
    const float* o = &hs[r * ONC + lane * 14];
    const float Wv0 = o[0], Wv1 = o[1], Wv2 = o[2], Wv3 = o[3], Wv4 = o[4];
    const float Hv0 = o[5], Hv1 = o[6], Hv2 = o[7], Hv3 = o[8], Hv4 = o[9];
    const float Dv0 = o[10], Dv1 = o[11], Dv2 = o[12], Dv3 = o[13];
    const float xv = x[(size_t)(b0 + r) * DIMX + lane];

    // widths: MIN_W + (1-5*MIN_W) * softmax(W)
    float mw = fmaxf(fmaxf(fmaxf(Wv0, Wv1), fmaxf(Wv2, Wv3)), Wv4);
    float e0 = expf(Wv0 - mw), e1 = expf(Wv1 - mw), e2 = expf(Wv2 - mw),
          e3 = expf(Wv3 - mw), e4 = expf(Wv4 - mw);
    float inv = 0.995f / (e0 + e1 + e2 + e3 + e4);
    const float wd0 = 0.001f + e0 * inv, wd1 = 0.001f + e1 * inv,
                wd2 = 0.001f + e2 * inv, wd3 = 0.001f + e3 * inv;
    const float c1 = wd0, c2 = c1 + wd1, c3 = c2 + wd2, c4 = c3 + wd3; // cw5 := 1
    const float wi0 = c1, wi1 = c2 - c1, wi2 = c3 - c2, wi3 = c4 - c3, wi4 = 1.f - c4;

    // heights
    float mh = fmaxf(fmaxf(fmaxf(Hv0, Hv1), fmaxf(Hv2, Hv3)), Hv4);
    float f0 = expf(Hv0 - mh), f1e = expf(Hv1 - mh), f2e = expf(Hv2 - mh),
          f3e = expf(Hv3 - mh), f4e = expf(Hv4 - mh);
    float invh = 0.995f / (f0 + f1e + f2e + f3e + f4e);
    const float hd0 = 0.001f + f0 * invh, hd1 = 0.001f + f1e * invh,
                hd2 = 0.001f + f2e * invh, hd3 = 0.001f + f3e * invh;
    const float g1c = hd0, g2c = g1c + hd1, g3c = g2c + hd2, g4c = g3c + hd3; // ch5 := 1
    const float hi0 = g1c, hi1 = g2c - g1c, hi2 = g3c - g2c, hi3 = g4c - g3c, hi4 = 1.f - g4c;

    // derivs: pad = MIN_D + softplus(CONST) = 1.0 exactly
    const float dv1 = 0.001f + softplusf(Dv0), dv2 = 0.001f + softplusf(Dv1),
                dv3 = 0.001f + softplusf(Dv2), dv4 = 0.001f + softplusf(Dv3);

    const float s = 1.f / (1.f + expf(-xv));
    const int idx = (int)(s >= c1) + (int)(s >= c2) + (int)(s >= c3) + (int)(s >= c4);

    const float in_cw = idx == 0 ? 0.f : idx == 1 ? c1  : idx == 2 ? c2  : idx == 3 ? c3  : c4;
    const float in_w  = idx == 0 ? wi0 : idx == 1 ? wi1 : idx == 2 ? wi2 : idx == 3 ? wi3 : wi4;
    const float in_h  = idx == 0 ? hi0 : idx == 1 ? hi1 : idx == 2 ? hi2 : idx == 3 ? hi3 : hi4;
    const float in_ch = idx == 0 ? 0.f : idx == 1 ? g1c : idx == 2 ? g2c : idx == 3 ? g3c : g4c;
    const float d0    = idx == 0 ? 1.f : idx == 1 ? dv1 : idx == 2 ? dv2 : idx == 3 ? dv3 : dv4;
    const float d1    = idx == 0 ? dv1 : idx == 1 ? dv2 : idx == 2 ? dv3 : idx == 3 ? dv4 : 1.f;

    const float delta = in_h / in_w;
    const float th  = (s - in_cw) / in_w;
    const float omt = 1.f - th;
    const float t1  = th * omt;
    const float num = in_h * (delta * th * th + d0 * t1);
    const float den = delta + (d0 + d1 - 2.f * delta) * t1;
    float outv = in_ch + num / den;
    const float dnum = delta * delta * (d1 * th * th + 2.f * delta * t1 + d0 * omt * omt);
    const float lad_rqs = logf(dnum) - 2.f * logf(den);
    outv = outv * 0.999998f + 1e-6f;
    const float lo = logf(outv), l1m = logf(1.f - outv);
    const float logds = -softplusf(-xv) - softplusf(xv);

    zout[(size_t)(b0 + r) * DIMX + lane] = lo - l1m;
    const float ladd = logds + lad_rqs - lo - l1m;
    const float tot = wave_sum64(ladd);
    if (lane == 0) ladout[b0 + r] = tot;
  }
}

// ---------------------------------------------------------------------------
extern "C" void kernel_launch(void* const* d_in, const int* in_sizes, int n_in,
                              void* d_out, int out_size, void* d_ws, size_t ws_size,
                              hipStream_t stream) {
  const float* x   = (const float*)d_in[0];
  const float* feat= (const float*)d_in[1];
  const float* w1  = (const float*)d_in[2];   // [WIDTH][IN1]  (pre-masked)
  const float* b1  = (const float*)d_in[3];
  const float* g1  = (const float*)d_in[4];
  const float* be1 = (const float*)d_in[5];
  const float* w2  = (const float*)d_in[6];   // [WIDTH][WIDTH] (pre-masked)
  const float* b2  = (const float*)d_in[7];
  const float* g2  = (const float*)d_in[8];
  const float* be2 = (const float*)d_in[9];
  const float* w3  = (const float*)d_in[10];  // [ONC][WIDTH]  (pre-masked)
  const float* b3  = (const float*)d_in[11];
  // masks d_in[12..14] intentionally unused: weights are already masked and
  // the masks are 0/1, so re-applying them is a no-op.

  // workspace: k-major transposed weights (16.1 MB total)
  float* w1t = (float*)d_ws;                        // [IN1][WIDTH]
  float* w2t = w1t + (size_t)IN1 * WIDTH;           // [WIDTH][WIDTH]
  float* w3t = w2t + (size_t)WIDTH * WIDTH;         // [WIDTH][ONC]

  transpose_k<<<dim3(IN1 / 32,   WIDTH / 32), 256, 0, stream>>>(w1, w1t, WIDTH, IN1);
  transpose_k<<<dim3(WIDTH / 32, WIDTH / 32), 256, 0, stream>>>(w2, w2t, WIDTH, WIDTH);
  transpose_k<<<dim3(WIDTH / 32, ONC / 32),   256, 0, stream>>>(w3, w3t, ONC, WIDTH);

  float* zout   = (float*)d_out;
  float* ladout = zout + (size_t)BATCH * DIMX;
  nsf_fused<<<BATCH / BM, NT, 0, stream>>>(x, feat, w1t, b1, g1, be1,
                                           w2t, b2, g2, be2, w3t, b3,
                                           zout, ladout);
}

// Round 2
// 407.326 us; speedup vs baseline: 10.8528x; 10.8528x over previous
//
#include <hip/hip_runtime.h>
#include <math.h>

// Problem constants
#define BATCH   32768
#define DIMX    64
#define FEATD   128
#define IN1     192      // FEATDIM + DIM
#define WIDTH   1536
#define ONC     896      // DIM * (3K-1)

// Tiling
#define BM      32       // batch rows per block
#define NT      512      // 8 waves
#define H_LD    1544     // h row stride in bf16 elems (1536 + 8 pad)
#define IN_LD   200      // input row stride in bf16 elems (192 + 8 pad)
#define O_LD    904      // o row stride in f32 elems (896 + 8 pad)

typedef __attribute__((ext_vector_type(8))) short short8;
typedef __attribute__((ext_vector_type(4))) float f32x4;

#define MFMA_BF16(a,b,c) __builtin_amdgcn_mfma_f32_16x16x32_bf16((a),(b),(c),0,0,0)

__device__ __forceinline__ unsigned short f2bf(float f) {
  unsigned u = __builtin_bit_cast(unsigned, f);
  u += 0x7fffu + ((u >> 16) & 1u);            // round-to-nearest-even
  return (unsigned short)(u >> 16);
}
__device__ __forceinline__ float wave_sum64(float v) {
  #pragma unroll
  for (int o = 32; o > 0; o >>= 1) v += __shfl_xor(v, o, 64);
  return v;
}
__device__ __forceinline__ float softplusf(float t) {
  return fmaxf(t, 0.f) + log1pf(expf(-fabsf(t)));
}

// ---------------------------------------------------------------------------
// Pack weight W [N][K] f32 (pre-masked) into MFMA B-fragment tiles, bf16:
//   out[(kb*(N/16)+nb)*512 + lane*8 + j] = bf16( W[nb*16 + (lane&15)][kb*32 + (lane>>4)*8 + j] )
// One wave per 32x16 tile.
// ---------------------------------------------------------------------------
__global__ __launch_bounds__(256) void pack_w(const float* __restrict__ W,
                                              unsigned short* __restrict__ out,
                                              int N, int K) {
  const int wv = (blockIdx.x * 256 + threadIdx.x) >> 6;   // tile id
  const int lane = threadIdx.x & 63;
  const int ntiles = (K / 32) * (N / 16);
  if (wv >= ntiles) return;
  const int nbt = N / 16;
  const int kb = wv / nbt, nb = wv - kb * nbt;
  const int n = nb * 16 + (lane & 15);
  const int k = kb * 32 + (lane >> 4) * 8;
  const float* src = W + (size_t)n * K + k;
  const float4 v0 = *(const float4*)src;
  const float4 v1 = *(const float4*)(src + 4);
  short8 o;
  o[0] = (short)f2bf(v0.x); o[1] = (short)f2bf(v0.y);
  o[2] = (short)f2bf(v0.z); o[3] = (short)f2bf(v0.w);
  o[4] = (short)f2bf(v1.x); o[5] = (short)f2bf(v1.y);
  o[6] = (short)f2bf(v1.z); o[7] = (short)f2bf(v1.w);
  *(short8*)(out + ((size_t)wv * 64 + lane) * 8) = o;
}

// ---------------------------------------------------------------------------
// Fragment loads
// ---------------------------------------------------------------------------
__device__ __forceinline__ short8 lda_frag(const unsigned short* h, int ld,
                                           int rb, int kb, int l15, int l4) {
  return *(const short8*)(h + (size_t)(rb * 16 + l15) * ld + kb * 32 + l4 * 8);
}
__device__ __forceinline__ short8 ldb_frag(const unsigned short* p, int tile, int lane) {
  return *(const short8*)(p + ((size_t)tile * 64 + lane) * 8);
}

// ---------------------------------------------------------------------------
// bias + leaky + LayerNorm on MFMA C fragments (NB n-tiles per wave, 2 row-blocks)
// result written as bf16 into hbuf (row-major, stride H_LD).
// ---------------------------------------------------------------------------
template <int NB>
__device__ __forceinline__ void act_ln(f32x4 acc[2][NB],
    const float* __restrict__ bias, const float* __restrict__ gam,
    const float* __restrict__ bet, int colbase,
    unsigned short* hbuf, float* red, float* mstd,
    int t, int w, int l15, int l4)
{
  #pragma unroll
  for (int nb = 0; nb < NB; ++nb) {
    const float bb = bias[colbase + nb * 16 + l15];
    #pragma unroll
    for (int rb = 0; rb < 2; ++rb)
      #pragma unroll
      for (int i = 0; i < 4; ++i) {
        float v = acc[rb][nb][i] + bb;
        acc[rb][nb][i] = v > 0.f ? v : 0.2f * v;
      }
  }
  float s[2][4], q[2][4];
  #pragma unroll
  for (int rb = 0; rb < 2; ++rb)
    #pragma unroll
    for (int i = 0; i < 4; ++i) {
      float ss = 0.f, qq = 0.f;
      #pragma unroll
      for (int nb = 0; nb < NB; ++nb) {
        const float v = acc[rb][nb][i];
        ss += v; qq += v * v;
      }
      #pragma unroll
      for (int o = 1; o < 16; o <<= 1) { ss += __shfl_xor(ss, o, 64); qq += __shfl_xor(qq, o, 64); }
      s[rb][i] = ss; q[rb][i] = qq;
    }
  if (l15 == 0) {
    #pragma unroll
    for (int rb = 0; rb < 2; ++rb)
      #pragma unroll
      for (int i = 0; i < 4; ++i) {
        const int r = rb * 16 + l4 * 4 + i;
        red[w * 32 + r] = s[rb][i];
        red[256 + w * 32 + r] = q[rb][i];
      }
  }
  __syncthreads();
  if (t < 32) {
    float ss = 0.f, qq = 0.f;
    #pragma unroll
    for (int w8 = 0; w8 < 8; ++w8) { ss += red[w8 * 32 + t]; qq += red[256 + w8 * 32 + t]; }
    const float m = ss * (1.f / (float)WIDTH);
    const float v = qq * (1.f / (float)WIDTH) - m * m;
    mstd[t] = m;
    mstd[32 + t] = rsqrtf(fmaxf(v, 0.f) + 1e-5f);
  }
  __syncthreads();
  float mm[2][4], rr[2][4];
  #pragma unroll
  for (int rb = 0; rb < 2; ++rb)
    #pragma unroll
    for (int i = 0; i < 4; ++i) {
      const int r = rb * 16 + l4 * 4 + i;
      mm[rb][i] = mstd[r]; rr[rb][i] = mstd[32 + r];
    }
  #pragma unroll
  for (int nb = 0; nb < NB; ++nb) {
    const int col = colbase + nb * 16 + l15;
    const float gg = gam[col], ee = bet[col];
    #pragma unroll
    for (int rb = 0; rb < 2; ++rb)
      #pragma unroll
      for (int i = 0; i < 4; ++i) {
        const int r = rb * 16 + l4 * 4 + i;
        const float hv = (acc[rb][nb][i] - mm[rb][i]) * rr[rb][i] * gg + ee;
        hbuf[(size_t)r * H_LD + col] = f2bf(hv);
      }
  }
  __syncthreads();
}

// ---------------------------------------------------------------------------
// Fused kernel
// ---------------------------------------------------------------------------
__global__ __launch_bounds__(NT, 2) void nsf_fused(
    const float* __restrict__ x, const float* __restrict__ feat,
    const unsigned short* __restrict__ w1p, const float* __restrict__ b1,
    const float* __restrict__ g1, const float* __restrict__ be1,
    const unsigned short* __restrict__ w2p, const float* __restrict__ b2,
    const float* __restrict__ g2, const float* __restrict__ be2,
    const unsigned short* __restrict__ w3p, const float* __restrict__ b3,
    float* __restrict__ zout, float* __restrict__ ladout)
{
  __shared__ __align__(16) unsigned char smem[BM * O_LD * 4 + 2048 + 256];
  unsigned short* hbuf = (unsigned short*)smem;       // [32][H_LD] bf16 (aliased)
  float* obuf = (float*)smem;                         // [32][O_LD] f32  (aliased)
  float* red  = (float*)(smem + BM * O_LD * 4);       // 512 f32
  float* mstd = red + 512;                            // 64 f32

  const int t = threadIdx.x;
  const int lane = t & 63, w = t >> 6;
  const int l15 = lane & 15, l4 = lane >> 4;
  const int b0 = blockIdx.x * BM;

  // ---- stage concat([feat, x]) as bf16 into hbuf rows of stride IN_LD ----
  for (int idx = t; idx < BM * IN1; idx += NT) {
    const int r = idx / IN1, c = idx - r * IN1;
    const float v = (c < FEATD) ? feat[(size_t)(b0 + r) * FEATD + c]
                                : x[(size_t)(b0 + r) * DIMX + (c - FEATD)];
    hbuf[r * IN_LD + c] = f2bf(v);
  }
  __syncthreads();

  // ================= GEMM1: K=192 (6 kblks), cols w*192..+192 =================
  f32x4 acc[2][12];
  #pragma unroll
  for (int rb = 0; rb < 2; ++rb)
    #pragma unroll
    for (int nb = 0; nb < 12; ++nb) acc[rb][nb] = (f32x4){0.f, 0.f, 0.f, 0.f};

  #pragma unroll 1
  for (int kb = 0; kb < 6; ++kb) {
    const short8 a0 = lda_frag(hbuf, IN_LD, 0, kb, l15, l4);
    const short8 a1 = lda_frag(hbuf, IN_LD, 1, kb, l15, l4);
    short8 bv[12];
    #pragma unroll
    for (int nb = 0; nb < 12; ++nb) bv[nb] = ldb_frag(w1p, kb * 96 + w * 12 + nb, lane);
    #pragma unroll
    for (int nb = 0; nb < 12; ++nb) {
      acc[0][nb] = MFMA_BF16(a0, bv[nb], acc[0][nb]);
      acc[1][nb] = MFMA_BF16(a1, bv[nb], acc[1][nb]);
    }
  }
  act_ln<12>(acc, b1, g1, be1, w * 192, hbuf, red, mstd, t, w, l15, l4);

  // ================= GEMM2: K=1536 (48 kblks), registers double-buffered =====
  #pragma unroll
  for (int rb = 0; rb < 2; ++rb)
    #pragma unroll
    for (int nb = 0; nb < 12; ++nb) acc[rb][nb] = (f32x4){0.f, 0.f, 0.f, 0.f};

  {
    short8 bA[12], bB[12];
    #pragma unroll
    for (int nb = 0; nb < 12; ++nb) bA[nb] = ldb_frag(w2p, 0 * 96 + w * 12 + nb, lane);
    #pragma unroll 1
    for (int kb = 0; kb < 48; kb += 2) {
      #pragma unroll
      for (int nb = 0; nb < 12; ++nb) bB[nb] = ldb_frag(w2p, (kb + 1) * 96 + w * 12 + nb, lane);
      {
        const short8 a0 = lda_frag(hbuf, H_LD, 0, kb, l15, l4);
        const short8 a1 = lda_frag(hbuf, H_LD, 1, kb, l15, l4);
        #pragma unroll
        for (int nb = 0; nb < 12; ++nb) {
          acc[0][nb] = MFMA_BF16(a0, bA[nb], acc[0][nb]);
          acc[1][nb] = MFMA_BF16(a1, bA[nb], acc[1][nb]);
        }
      }
      if (kb + 2 < 48) {
        #pragma unroll
        for (int nb = 0; nb < 12; ++nb) bA[nb] = ldb_frag(w2p, (kb + 2) * 96 + w * 12 + nb, lane);
      }
      {
        const short8 a0 = lda_frag(hbuf, H_LD, 0, kb + 1, l15, l4);
        const short8 a1 = lda_frag(hbuf, H_LD, 1, kb + 1, l15, l4);
        #pragma unroll
        for (int nb = 0; nb < 12; ++nb) {
          acc[0][nb] = MFMA_BF16(a0, bB[nb], acc[0][nb]);
          acc[1][nb] = MFMA_BF16(a1, bB[nb], acc[1][nb]);
        }
      }
    }
  }
  act_ln<12>(acc, b2, g2, be2, w * 192, hbuf, red, mstd, t, w, l15, l4);

  // ================= GEMM3: N=896, cols w*112..+112 (7 tiles) =================
  f32x4 acc3[2][7];
  #pragma unroll
  for (int rb = 0; rb < 2; ++rb)
    #pragma unroll
    for (int nb = 0; nb < 7; ++nb) acc3[rb][nb] = (f32x4){0.f, 0.f, 0.f, 0.f};

  {
    short8 bA[7], bB[7];
    #pragma unroll
    for (int nb = 0; nb < 7; ++nb) bA[nb] = ldb_frag(w3p, 0 * 56 + w * 7 + nb, lane);
    #pragma unroll 1
    for (int kb = 0; kb < 48; kb += 2) {
      #pragma unroll
      for (int nb = 0; nb < 7; ++nb) bB[nb] = ldb_frag(w3p, (kb + 1) * 56 + w * 7 + nb, lane);
      {
        const short8 a0 = lda_frag(hbuf, H_LD, 0, kb, l15, l4);
        const short8 a1 = lda_frag(hbuf, H_LD, 1, kb, l15, l4);
        #pragma unroll
        for (int nb = 0; nb < 7; ++nb) {
          acc3[0][nb] = MFMA_BF16(a0, bA[nb], acc3[0][nb]);
          acc3[1][nb] = MFMA_BF16(a1, bA[nb], acc3[1][nb]);
        }
      }
      if (kb + 2 < 48) {
        #pragma unroll
        for (int nb = 0; nb < 7; ++nb) bA[nb] = ldb_frag(w3p, (kb + 2) * 56 + w * 7 + nb, lane);
      }
      {
        const short8 a0 = lda_frag(hbuf, H_LD, 0, kb + 1, l15, l4);
        const short8 a1 = lda_frag(hbuf, H_LD, 1, kb + 1, l15, l4);
        #pragma unroll
        for (int nb = 0; nb < 7; ++nb) {
          acc3[0][nb] = MFMA_BF16(a0, bB[nb], acc3[0][nb]);
          acc3[1][nb] = MFMA_BF16(a1, bB[nb], acc3[1][nb]);
        }
      }
    }
  }
  __syncthreads();   // all h reads done before o overwrites the buffer
  {
    #pragma unroll
    for (int nb = 0; nb < 7; ++nb) {
      const int col = w * 112 + nb * 16 + l15;
      const float bb = b3[col];
      #pragma unroll
      for (int rb = 0; rb < 2; ++rb)
        #pragma unroll
        for (int i = 0; i < 4; ++i) {
          const int r = rb * 16 + l4 * 4 + i;
          obuf[(size_t)r * O_LD + col] = acc3[rb][nb][i] + bb;
        }
    }
  }
  __syncthreads();

  // ================= spline: wave w handles rows w*4..w*4+3, lane = dim ======
  #pragma unroll 1
  for (int i = 0; i < 4; ++i) {
    const int r = w * 4 + i;
    const float* o = &obuf[(size_t)r * O_LD + lane * 14];
    const float Wv0 = o[0], Wv1 = o[1], Wv2 = o[2], Wv3 = o[3], Wv4 = o[4];
    const float Hv0 = o[5], Hv1 = o[6], Hv2 = o[7], Hv3 = o[8], Hv4 = o[9];
    const float Dv0 = o[10], Dv1 = o[11], Dv2 = o[12], Dv3 = o[13];
    const float xv = x[(size_t)(b0 + r) * DIMX + lane];

    float mw = fmaxf(fmaxf(fmaxf(Wv0, Wv1), fmaxf(Wv2, Wv3)), Wv4);
    float e0 = expf(Wv0 - mw), e1 = expf(Wv1 - mw), e2 = expf(Wv2 - mw),
          e3 = expf(Wv3 - mw), e4 = expf(Wv4 - mw);
    float inv = 0.995f / (e0 + e1 + e2 + e3 + e4);
    const float wd0 = 0.001f + e0 * inv, wd1 = 0.001f + e1 * inv,
                wd2 = 0.001f + e2 * inv, wd3 = 0.001f + e3 * inv;
    const float c1 = wd0, c2 = c1 + wd1, c3 = c2 + wd2, c4 = c3 + wd3;
    const float wi0 = c1, wi1 = c2 - c1, wi2 = c3 - c2, wi3 = c4 - c3, wi4 = 1.f - c4;

    float mh = fmaxf(fmaxf(fmaxf(Hv0, Hv1), fmaxf(Hv2, Hv3)), Hv4);
    float f0 = expf(Hv0 - mh), f1e = expf(Hv1 - mh), f2e = expf(Hv2 - mh),
          f3e = expf(Hv3 - mh), f4e = expf(Hv4 - mh);
    float invh = 0.995f / (f0 + f1e + f2e + f3e + f4e);
    const float hd0 = 0.001f + f0 * invh, hd1 = 0.001f + f1e * invh,
                hd2 = 0.001f + f2e * invh, hd3 = 0.001f + f3e * invh;
    const float g1c = hd0, g2c = g1c + hd1, g3c = g2c + hd2, g4c = g3c + hd3;
    const float hi0 = g1c, hi1 = g2c - g1c, hi2 = g3c - g2c, hi3 = g4c - g3c, hi4 = 1.f - g4c;

    const float dv1 = 0.001f + softplusf(Dv0), dv2 = 0.001f + softplusf(Dv1),
                dv3 = 0.001f + softplusf(Dv2), dv4 = 0.001f + softplusf(Dv3);

    const float s = 1.f / (1.f + expf(-xv));
    const int idx = (int)(s >= c1) + (int)(s >= c2) + (int)(s >= c3) + (int)(s >= c4);

    const float in_cw = idx == 0 ? 0.f : idx == 1 ? c1  : idx == 2 ? c2  : idx == 3 ? c3  : c4;
    const float in_w  = idx == 0 ? wi0 : idx == 1 ? wi1 : idx == 2 ? wi2 : idx == 3 ? wi3 : wi4;
    const float in_h  = idx == 0 ? hi0 : idx == 1 ? hi1 : idx == 2 ? hi2 : idx == 3 ? hi3 : hi4;
    const float in_ch = idx == 0 ? 0.f : idx == 1 ? g1c : idx == 2 ? g2c : idx == 3 ? g3c : g4c;
    const float d0    = idx == 0 ? 1.f : idx == 1 ? dv1 : idx == 2 ? dv2 : idx == 3 ? dv3 : dv4;
    const float d1    = idx == 0 ? dv1 : idx == 1 ? dv2 : idx == 2 ? dv3 : idx == 3 ? dv4 : 1.f;

    const float delta = in_h / in_w;
    const float th  = (s - in_cw) / in_w;
    const float omt = 1.f - th;
    const float t1  = th * omt;
    const float num = in_h * (delta * th * th + d0 * t1);
    const float den = delta + (d0 + d1 - 2.f * delta) * t1;
    float outv = in_ch + num / den;
    const float dnum = delta * delta * (d1 * th * th + 2.f * delta * t1 + d0 * omt * omt);
    const float lad_rqs = logf(dnum) - 2.f * logf(den);
    outv = outv * 0.999998f + 1e-6f;
    const float lo = logf(outv), l1m = logf(1.f - outv);
    const float logds = -softplusf(-xv) - softplusf(xv);

    zout[(size_t)(b0 + r) * DIMX + lane] = lo - l1m;
    const float ladd = logds + lad_rqs - lo - l1m;
    const float tot = wave_sum64(ladd);
    if (lane == 0) ladout[b0 + r] = tot;
  }
}

// ---------------------------------------------------------------------------
extern "C" void kernel_launch(void* const* d_in, const int* in_sizes, int n_in,
                              void* d_out, int out_size, void* d_ws, size_t ws_size,
                              hipStream_t stream) {
  const float* x   = (const float*)d_in[0];
  const float* feat= (const float*)d_in[1];
  const float* w1  = (const float*)d_in[2];   // [1536][192]  pre-masked
  const float* b1  = (const float*)d_in[3];
  const float* g1  = (const float*)d_in[4];
  const float* be1 = (const float*)d_in[5];
  const float* w2  = (const float*)d_in[6];   // [1536][1536] pre-masked
  const float* b2  = (const float*)d_in[7];
  const float* g2  = (const float*)d_in[8];
  const float* be2 = (const float*)d_in[9];
  const float* w3  = (const float*)d_in[10];  // [896][1536]  pre-masked
  const float* b3  = (const float*)d_in[11];
  // masks unused: weights arrive pre-masked (mask is 0/1, idempotent).

  unsigned short* w1p = (unsigned short*)d_ws;                 // 576 tiles
  unsigned short* w2p = w1p + (size_t)576 * 512;               // 4608 tiles
  unsigned short* w3p = w2p + (size_t)4608 * 512;              // 2688 tiles

  pack_w<<<144,  256, 0, stream>>>(w1, w1p, WIDTH, IN1);
  pack_w<<<1152, 256, 0, stream>>>(w2, w2p, WIDTH, WIDTH);
  pack_w<<<672,  256, 0, stream>>>(w3, w3p, ONC, WIDTH);

  float* zout   = (float*)d_out;
  float* ladout = zout + (size_t)BATCH * DIMX;
  nsf_fused<<<BATCH / BM, NT, 0, stream>>>(x, feat, w1p, b1, g1, be1,
                                           w2p, b2, g2, be2, w3p, b3,
                                           zout, ladout);
}